// Round 1
// baseline (860.364 us; speedup 1.0000x reference)
//
#include <hip/hip_runtime.h>
#include <math.h>

// Problem constants (from reference): N=50000, F=256, H=256, C=40, E=800000
// CURV=1, EPS=4e-3 -> maxnorm=0.996, MIN_NORM=1e-15

// ---------------- CSR build ----------------

__global__ void k_count(const int* __restrict__ dst, int* __restrict__ deg, int E) {
    int e = blockIdx.x * 256 + threadIdx.x;
    if (e < E) atomicAdd(&deg[dst[e]], 1);
}

__global__ __launch_bounds__(1024) void k_scan(const int* __restrict__ deg,
                                               int* __restrict__ offs,
                                               float* __restrict__ invc, int N) {
    __shared__ int s[1024];
    int tid = threadIdx.x;
    int running = 0;
    for (int base = 0; base < N; base += 1024) {
        int i = base + tid;
        int v = (i < N) ? deg[i] : 0;
        if (i < N) invc[i] = 1.0f / (float)max(v, 1);
        s[tid] = v;
        __syncthreads();
        for (int d = 1; d < 1024; d <<= 1) {
            int t = (tid >= d) ? s[tid - d] : 0;
            __syncthreads();
            s[tid] += t;
            __syncthreads();
        }
        int incl = s[tid];
        if (i < N) offs[i] = running + incl - v;   // exclusive
        int tot = s[1023];
        __syncthreads();
        running += tot;
    }
    if (tid == 0) offs[N] = running;
}

__global__ void k_scatter(const int* __restrict__ src, const int* __restrict__ dst,
                          const int* __restrict__ offs, int* __restrict__ cursor,
                          int* __restrict__ ssrc, int E) {
    int e = blockIdx.x * 256 + threadIdx.x;
    if (e >= E) return;
    int d = dst[e];
    int pos = offs[d] + atomicAdd(&cursor[d], 1);
    ssrc[pos] = src[e];
}

// ---------------- GEMM0: Y[N,512] = x[N,256] @ [Wl0 | Wr0] ----------------
// 64x64 tile, K-chunk 32, 256 threads, 4x4 per thread, A transposed in LDS.

__global__ __launch_bounds__(256) void gemm0(const float* __restrict__ X,
                                             const float* __restrict__ Wl,
                                             const float* __restrict__ Wr,
                                             float* __restrict__ Y, int N) {
    __shared__ __align__(16) float Alds[32][68];  // [k][node]
    __shared__ __align__(16) float Blds[32][68];  // [k][col]
    int m0 = blockIdx.x * 64;
    int bn = blockIdx.y;                  // 0..7 -> output cols bn*64..bn*64+63
    const float* B = (bn < 4) ? Wl : Wr;  // both are [256,256] row-major
    int c0 = (bn & 3) * 64;
    int tid = threadIdx.x;
    int ty = tid >> 4, tx = tid & 15;
    float acc[4][4] = {};

    for (int ko = 0; ko < 256; ko += 32) {
        // stage A transposed: 64 nodes x 32 k
        #pragma unroll
        for (int r = 0; r < 2; ++r) {
            int idx = tid + r * 256;
            int node = idx >> 3;
            int k4 = idx & 7;
            float4 v = make_float4(0.f, 0.f, 0.f, 0.f);
            int gn = m0 + node;
            if (gn < N) v = *(const float4*)&X[gn * 256 + ko + k4 * 4];
            Alds[k4 * 4 + 0][node] = v.x;
            Alds[k4 * 4 + 1][node] = v.y;
            Alds[k4 * 4 + 2][node] = v.z;
            Alds[k4 * 4 + 3][node] = v.w;
        }
        // stage B: 32 k x 64 cols
        #pragma unroll
        for (int r = 0; r < 2; ++r) {
            int idx = tid + r * 256;
            int kr = idx >> 4;
            int c4 = (idx & 15) * 4;
            float4 v = *(const float4*)&B[(ko + kr) * 256 + c0 + c4];
            *(float4*)&Blds[kr][c4] = v;
        }
        __syncthreads();
        #pragma unroll
        for (int kk = 0; kk < 32; ++kk) {
            float4 av = *(const float4*)&Alds[kk][ty * 4];
            float4 bv = *(const float4*)&Blds[kk][tx * 4];
            float a[4] = {av.x, av.y, av.z, av.w};
            float b[4] = {bv.x, bv.y, bv.z, bv.w};
            #pragma unroll
            for (int i = 0; i < 4; ++i)
                #pragma unroll
                for (int j = 0; j < 4; ++j) acc[i][j] += a[i] * b[j];
        }
        __syncthreads();
    }
    #pragma unroll
    for (int i = 0; i < 4; ++i) {
        int gn = m0 + ty * 4 + i;
        if (gn < N) {
            float4 v = make_float4(acc[i][0], acc[i][1], acc[i][2], acc[i][3]);
            *(float4*)&Y[(size_t)gn * 512 + bn * 64 + tx * 4] = v;
        }
    }
}

// ---------------- combine0: h = relu(agg(Y_l)/cnt + bl0 + Y_r) ----------------
// one wave per node, lane handles 4 contiguous cols (float4)

__global__ __launch_bounds__(256) void combine0(const float* __restrict__ Y,
                                                const int* __restrict__ offs,
                                                const int* __restrict__ ssrc,
                                                const float* __restrict__ invc,
                                                const float* __restrict__ bl0,
                                                float* __restrict__ H, int N) {
    int wv = threadIdx.x >> 6, lane = threadIdx.x & 63;
    int n = blockIdx.x * 4 + wv;
    if (n >= N) return;
    int e0 = offs[n], e1 = offs[n + 1];
    float4 acc = make_float4(0.f, 0.f, 0.f, 0.f);
    for (int e = e0; e < e1; ++e) {
        int s = ssrc[e];
        float4 v = *(const float4*)&Y[(size_t)s * 512 + lane * 4];
        acc.x += v.x; acc.y += v.y; acc.z += v.z; acc.w += v.w;
    }
    float ic = invc[n];
    float4 b = *(const float4*)&bl0[lane * 4];
    float4 yr = *(const float4*)&Y[(size_t)n * 512 + 256 + lane * 4];
    float4 h;
    h.x = fmaxf(acc.x * ic + b.x + yr.x, 0.f);
    h.y = fmaxf(acc.y * ic + b.y + yr.y, 0.f);
    h.z = fmaxf(acc.z * ic + b.z + yr.z, 0.f);
    h.w = fmaxf(acc.w * ic + b.w + yr.w, 0.f);
    *(float4*)&H[(size_t)n * 256 + lane * 4] = h;
}

// ---------------- GEMM1: Z[N,80] = H[N,256] @ [Wl1 | Wr1] ----------------
// 64 nodes per block; 4 waves, each wave owns 20 output cols (wave-uniform -> s_loads)

__global__ __launch_bounds__(256) void gemm1(const float* __restrict__ Hm,
                                             const float* __restrict__ Wl1,
                                             const float* __restrict__ Wr1,
                                             float* __restrict__ Z, int N) {
    __shared__ float Alds[64 * 65];  // [k][node], stride 65
    int m0 = blockIdx.x * 64;
    int tid = threadIdx.x;
    int lane = tid & 63;
    int w = __builtin_amdgcn_readfirstlane(tid >> 6);  // 0..3, wave-uniform
    const float* Bp = (w < 2) ? Wl1 : Wr1;             // [256,40] row-major
    int cbase = (w & 1) * 20;
    float acc[20] = {};

    for (int ko = 0; ko < 256; ko += 64) {
        #pragma unroll
        for (int r = 0; r < 4; ++r) {
            int idx = tid + r * 256;
            int node = idx >> 4;
            int k4 = (idx & 15) * 4;
            float4 v = make_float4(0.f, 0.f, 0.f, 0.f);
            int gn = m0 + node;
            if (gn < N) v = *(const float4*)&Hm[(size_t)gn * 256 + ko + k4];
            Alds[(k4 + 0) * 65 + node] = v.x;
            Alds[(k4 + 1) * 65 + node] = v.y;
            Alds[(k4 + 2) * 65 + node] = v.z;
            Alds[(k4 + 3) * 65 + node] = v.w;
        }
        __syncthreads();
        #pragma unroll 4
        for (int k = 0; k < 64; ++k) {
            float a = Alds[k * 65 + lane];
            const float* brow = &Bp[(ko + k) * 40 + cbase];
            #pragma unroll
            for (int c = 0; c < 20; ++c) acc[c] += a * brow[c];
        }
        __syncthreads();
    }
    int gn = m0 + lane;
    if (gn < N) {
        #pragma unroll
        for (int c = 0; c < 20; ++c) Z[(size_t)gn * 80 + w * 20 + c] = acc[c];
    }
}

// ---------------- combine1: h2 = agg(Z_l)/cnt + bl1 + Z_r ----------------

__global__ __launch_bounds__(256) void combine1(const float* __restrict__ Z,
                                                const int* __restrict__ offs,
                                                const int* __restrict__ ssrc,
                                                const float* __restrict__ invc,
                                                const float* __restrict__ bl1,
                                                float* __restrict__ H2, int N) {
    int wv = threadIdx.x >> 6, lane = threadIdx.x & 63;
    int n = blockIdx.x * 4 + wv;
    if (n >= N) return;
    if (lane >= 40) return;
    int e0 = offs[n], e1 = offs[n + 1];
    float acc = 0.f;
    for (int e = e0; e < e1; ++e) {
        int s = ssrc[e];
        acc += Z[(size_t)s * 80 + lane];
    }
    float v = acc * invc[n] + bl1[lane] + Z[(size_t)n * 80 + 40 + lane];
    H2[(size_t)n * 40 + lane] = v;
}

// ---------------- final: outer -> proj -> logmap0 -> @W_lin+b -> expmap0 -> proj -> log_softmax
// u[n,k] = beta_n * sum_ij g_i g_j W[(i*40+j)*40+k] + b[k]
// block: 64 nodes, 4 waves; wave kq owns k-range kq*10..kq*10+9 (wave-uniform W -> s_loads)

__global__ __launch_bounds__(256) void k_final(const float* __restrict__ H2,
                                               const float* __restrict__ W,
                                               const float* __restrict__ bl,
                                               float* __restrict__ out, int N) {
    __shared__ float G[64 * 41];
    __shared__ float U[64 * 41];
    int tid = threadIdx.x;
    int m0 = blockIdx.x * 64;
    for (int idx = tid; idx < 64 * 40; idx += 256) {
        int nl = idx / 40;
        int k = idx - nl * 40;
        int gn = m0 + nl;
        G[nl * 41 + k] = (gn < N) ? H2[(size_t)gn * 40 + k] : 0.f;
    }
    __syncthreads();

    int lane = tid & 63;
    int kq = __builtin_amdgcn_readfirstlane(tid >> 6);  // 0..3
    float gr[40];
    #pragma unroll
    for (int j = 0; j < 40; ++j) gr[j] = G[lane * 41 + j];

    float accv[10] = {};
    for (int i = 0; i < 40; ++i) {
        float gi = G[lane * 41 + i];
        const float* wbase = &W[(size_t)(i * 40) * 40 + kq * 10];
        #pragma unroll
        for (int j = 0; j < 40; ++j) {
            float coef = gi * gr[j];
            #pragma unroll
            for (int t = 0; t < 10; ++t) accv[t] += coef * wbase[j * 40 + t];
        }
    }
    #pragma unroll
    for (int t = 0; t < 10; ++t) U[lane * 41 + kq * 10 + t] = accv[t];
    __syncthreads();

    if (tid < 64) {
        int gn = m0 + tid;
        if (gn < N) {
            float s2 = 0.f;
            #pragma unroll
            for (int i = 0; i < 40; ++i) {
                float g = G[tid * 41 + i];
                s2 += g * g;
            }
            // proj(outer): ||outer||_F == s2
            float norm0 = fmaxf(s2, 1e-15f);
            float scale = (norm0 > 0.996f) ? (0.996f / norm0) : 1.0f;
            // logmap0
            float pn = fmaxf(s2 * scale, 1e-15f);
            float arg = fminf(pn, 1.0f - 1e-6f);
            float beta = atanhf(arg) / pn * scale;
            // u = beta * S + b
            float u[40];
            float un2 = 0.f;
            #pragma unroll
            for (int k = 0; k < 40; ++k) {
                u[k] = beta * U[tid * 41 + k] + bl[k];
                un2 += u[k] * u[k];
            }
            // expmap0
            float un = fmaxf(sqrtf(un2), 1e-15f);
            float gma = tanhf(un) / un;
            float v[40];
            float nv2 = 0.f;
            #pragma unroll
            for (int k = 0; k < 40; ++k) {
                v[k] = gma * u[k];
                nv2 += v[k] * v[k];
            }
            // proj
            float nv = fmaxf(sqrtf(nv2), 1e-15f);
            float ps = (nv > 0.996f) ? (0.996f / nv) : 1.0f;
            float mx = -1e30f;
            #pragma unroll
            for (int k = 0; k < 40; ++k) {
                v[k] *= ps;
                mx = fmaxf(mx, v[k]);
            }
            float se = 0.f;
            #pragma unroll
            for (int k = 0; k < 40; ++k) se += expf(v[k] - mx);
            float lse = logf(se);
            #pragma unroll
            for (int k = 0; k < 40; ++k) out[(size_t)gn * 40 + k] = v[k] - mx - lse;
        }
    }
}

// ---------------- launch ----------------

extern "C" void kernel_launch(void* const* d_in, const int* in_sizes, int n_in,
                              void* d_out, int out_size, void* d_ws, size_t ws_size,
                              hipStream_t stream) {
    const float* x    = (const float*)d_in[0];
    const int*   ei   = (const int*)d_in[1];
    const float* Wl0  = (const float*)d_in[2];
    const float* bl0  = (const float*)d_in[3];
    const float* Wr0  = (const float*)d_in[4];
    const float* Wl1  = (const float*)d_in[5];
    const float* bl1  = (const float*)d_in[6];
    const float* Wr1  = (const float*)d_in[7];
    const float* Wlin = (const float*)d_in[8];
    const float* blin = (const float*)d_in[9];
    int N = in_sizes[0] / 256;
    int E = in_sizes[1] / 2;
    const int* src = ei;
    const int* dst = ei + E;

    char* ws = (char*)d_ws;
    size_t off = 0;
    auto carve = [&](size_t bytes) -> char* {
        char* p = ws + off;
        off = (off + bytes + 255) & ~(size_t)255;
        return p;
    };
    int*   deg    = (int*)carve((size_t)N * 4);
    int*   cursor = (int*)carve((size_t)N * 4);
    int*   offs   = (int*)carve((size_t)(N + 1) * 4);
    float* invc   = (float*)carve((size_t)N * 4);
    int*   ssrc   = (int*)carve((size_t)E * 4);
    float* Y      = (float*)carve((size_t)N * 512 * 4);
    float* Hb     = (float*)carve((size_t)N * 256 * 4);
    float* Z      = (float*)carve((size_t)N * 80 * 4);
    float* H2     = (float*)carve((size_t)N * 40 * 4);

    hipMemsetAsync(deg, 0, (size_t)N * 4, stream);
    hipMemsetAsync(cursor, 0, (size_t)N * 4, stream);

    k_count<<<(E + 255) / 256, 256, 0, stream>>>(dst, deg, E);
    k_scan<<<1, 1024, 0, stream>>>(deg, offs, invc, N);
    k_scatter<<<(E + 255) / 256, 256, 0, stream>>>(src, dst, offs, cursor, ssrc, E);
    gemm0<<<dim3((N + 63) / 64, 8), 256, 0, stream>>>(x, Wl0, Wr0, Y, N);
    combine0<<<(N + 3) / 4, 256, 0, stream>>>(Y, offs, ssrc, invc, bl0, Hb, N);
    gemm1<<<(N + 63) / 64, 256, 0, stream>>>(Hb, Wl1, Wr1, Z, N);
    combine1<<<(N + 3) / 4, 256, 0, stream>>>(Z, offs, ssrc, invc, bl1, H2, N);
    k_final<<<(N + 63) / 64, 256, 0, stream>>>(H2, Wlin, blin, (float*)d_out, N);
}

// Round 2
// 810.042 us; speedup vs baseline: 1.0621x; 1.0621x over previous
//
#include <hip/hip_runtime.h>
#include <math.h>

// Problem constants (from reference): N=50000, F=256, H=256, C=40, E=800000
// CURV=1, EPS=4e-3 -> maxnorm=0.996, MIN_NORM=1e-15

typedef short bf16x8 __attribute__((ext_vector_type(8)));
typedef float f32x4 __attribute__((ext_vector_type(4)));

// pack two fp32 -> bf16x2 (round-half-up: add 0x8000 then take high 16) via v_perm
__device__ inline unsigned pack_bf16_hu(float a, float b) {
    unsigned ua = __float_as_uint(a) + 0x8000u;
    unsigned ub = __float_as_uint(b) + 0x8000u;
    return __builtin_amdgcn_perm(ub, ua, 0x07060302u);
}

__device__ inline unsigned short f2bf_rne(float x) {
    unsigned u = __float_as_uint(x);
    unsigned r = (u + 0x7fffu + ((u >> 16) & 1u)) >> 16;
    return (unsigned short)r;
}

// ---------------- CSR build ----------------

__global__ void k_count(const int* __restrict__ dst, int* __restrict__ deg, int E) {
    int e = blockIdx.x * 256 + threadIdx.x;
    if (e < E) atomicAdd(&deg[dst[e]], 1);
}

__global__ __launch_bounds__(1024) void k_scan(const int* __restrict__ deg,
                                               int* __restrict__ offs,
                                               float* __restrict__ invc, int N) {
    __shared__ int s[1024];
    int tid = threadIdx.x;
    int running = 0;
    for (int base = 0; base < N; base += 1024) {
        int i = base + tid;
        int v = (i < N) ? deg[i] : 0;
        if (i < N) invc[i] = 1.0f / (float)max(v, 1);
        s[tid] = v;
        __syncthreads();
        for (int d = 1; d < 1024; d <<= 1) {
            int t = (tid >= d) ? s[tid - d] : 0;
            __syncthreads();
            s[tid] += t;
            __syncthreads();
        }
        int incl = s[tid];
        if (i < N) offs[i] = running + incl - v;   // exclusive
        int tot = s[1023];
        __syncthreads();
        running += tot;
    }
    if (tid == 0) offs[N] = running;
}

__global__ void k_scatter(const int* __restrict__ src, const int* __restrict__ dst,
                          const int* __restrict__ offs, int* __restrict__ cursor,
                          int* __restrict__ ssrc, int E) {
    int e = blockIdx.x * 256 + threadIdx.x;
    if (e >= E) return;
    int d = dst[e];
    int pos = offs[d] + atomicAdd(&cursor[d], 1);
    ssrc[pos] = src[e];
}

// ---------------- GEMM0: Y[N,512] = x[N,256] @ [Wl0 | Wr0] ----------------

__global__ __launch_bounds__(256) void gemm0(const float* __restrict__ X,
                                             const float* __restrict__ Wl,
                                             const float* __restrict__ Wr,
                                             float* __restrict__ Y, int N) {
    __shared__ __align__(16) float Alds[32][68];  // [k][node]
    __shared__ __align__(16) float Blds[32][68];  // [k][col]
    int m0 = blockIdx.x * 64;
    int bn = blockIdx.y;                  // 0..7 -> output cols bn*64..bn*64+63
    const float* B = (bn < 4) ? Wl : Wr;  // both are [256,256] row-major
    int c0 = (bn & 3) * 64;
    int tid = threadIdx.x;
    int ty = tid >> 4, tx = tid & 15;
    float acc[4][4] = {};

    for (int ko = 0; ko < 256; ko += 32) {
        #pragma unroll
        for (int r = 0; r < 2; ++r) {
            int idx = tid + r * 256;
            int node = idx >> 3;
            int k4 = idx & 7;
            float4 v = make_float4(0.f, 0.f, 0.f, 0.f);
            int gn = m0 + node;
            if (gn < N) v = *(const float4*)&X[gn * 256 + ko + k4 * 4];
            Alds[k4 * 4 + 0][node] = v.x;
            Alds[k4 * 4 + 1][node] = v.y;
            Alds[k4 * 4 + 2][node] = v.z;
            Alds[k4 * 4 + 3][node] = v.w;
        }
        #pragma unroll
        for (int r = 0; r < 2; ++r) {
            int idx = tid + r * 256;
            int kr = idx >> 4;
            int c4 = (idx & 15) * 4;
            float4 v = *(const float4*)&B[(ko + kr) * 256 + c0 + c4];
            *(float4*)&Blds[kr][c4] = v;
        }
        __syncthreads();
        #pragma unroll
        for (int kk = 0; kk < 32; ++kk) {
            float4 av = *(const float4*)&Alds[kk][ty * 4];
            float4 bv = *(const float4*)&Blds[kk][tx * 4];
            float a[4] = {av.x, av.y, av.z, av.w};
            float b[4] = {bv.x, bv.y, bv.z, bv.w};
            #pragma unroll
            for (int i = 0; i < 4; ++i)
                #pragma unroll
                for (int j = 0; j < 4; ++j) acc[i][j] += a[i] * b[j];
        }
        __syncthreads();
    }
    #pragma unroll
    for (int i = 0; i < 4; ++i) {
        int gn = m0 + ty * 4 + i;
        if (gn < N) {
            float4 v = make_float4(acc[i][0], acc[i][1], acc[i][2], acc[i][3]);
            *(float4*)&Y[(size_t)gn * 512 + bn * 64 + tx * 4] = v;
        }
    }
}

// ---------------- combine0 ----------------

__global__ __launch_bounds__(256) void combine0(const float* __restrict__ Y,
                                                const int* __restrict__ offs,
                                                const int* __restrict__ ssrc,
                                                const float* __restrict__ invc,
                                                const float* __restrict__ bl0,
                                                float* __restrict__ H, int N) {
    int wv = threadIdx.x >> 6, lane = threadIdx.x & 63;
    int n = blockIdx.x * 4 + wv;
    if (n >= N) return;
    int e0 = offs[n], e1 = offs[n + 1];
    float4 acc = make_float4(0.f, 0.f, 0.f, 0.f);
    for (int e = e0; e < e1; ++e) {
        int s = ssrc[e];
        float4 v = *(const float4*)&Y[(size_t)s * 512 + lane * 4];
        acc.x += v.x; acc.y += v.y; acc.z += v.z; acc.w += v.w;
    }
    float ic = invc[n];
    float4 b = *(const float4*)&bl0[lane * 4];
    float4 yr = *(const float4*)&Y[(size_t)n * 512 + 256 + lane * 4];
    float4 h;
    h.x = fmaxf(acc.x * ic + b.x + yr.x, 0.f);
    h.y = fmaxf(acc.y * ic + b.y + yr.y, 0.f);
    h.z = fmaxf(acc.z * ic + b.z + yr.z, 0.f);
    h.w = fmaxf(acc.w * ic + b.w + yr.w, 0.f);
    *(float4*)&H[(size_t)n * 256 + lane * 4] = h;
}

// ---------------- GEMM1: Z[N,80] = H[N,256] @ [Wl1 | Wr1] ----------------

__global__ __launch_bounds__(256) void gemm1(const float* __restrict__ Hm,
                                             const float* __restrict__ Wl1,
                                             const float* __restrict__ Wr1,
                                             float* __restrict__ Z, int N) {
    __shared__ float Alds[64 * 65];  // [k][node], stride 65
    int m0 = blockIdx.x * 64;
    int tid = threadIdx.x;
    int lane = tid & 63;
    int w = __builtin_amdgcn_readfirstlane(tid >> 6);  // 0..3, wave-uniform
    const float* Bp = (w < 2) ? Wl1 : Wr1;             // [256,40] row-major
    int cbase = (w & 1) * 20;
    float acc[20] = {};

    for (int ko = 0; ko < 256; ko += 64) {
        #pragma unroll
        for (int r = 0; r < 4; ++r) {
            int idx = tid + r * 256;
            int node = idx >> 4;
            int k4 = (idx & 15) * 4;
            float4 v = make_float4(0.f, 0.f, 0.f, 0.f);
            int gn = m0 + node;
            if (gn < N) v = *(const float4*)&Hm[(size_t)gn * 256 + ko + k4];
            Alds[(k4 + 0) * 65 + node] = v.x;
            Alds[(k4 + 1) * 65 + node] = v.y;
            Alds[(k4 + 2) * 65 + node] = v.z;
            Alds[(k4 + 3) * 65 + node] = v.w;
        }
        __syncthreads();
        #pragma unroll 4
        for (int k = 0; k < 64; ++k) {
            float a = Alds[k * 65 + lane];
            const float* brow = &Bp[(ko + k) * 40 + cbase];
            #pragma unroll
            for (int c = 0; c < 20; ++c) acc[c] += a * brow[c];
        }
        __syncthreads();
    }
    int gn = m0 + lane;
    if (gn < N) {
        #pragma unroll
        for (int c = 0; c < 20; ++c) Z[(size_t)gn * 80 + w * 20 + c] = acc[c];
    }
}

// ---------------- combine1 ----------------

__global__ __launch_bounds__(256) void combine1(const float* __restrict__ Z,
                                                const int* __restrict__ offs,
                                                const int* __restrict__ ssrc,
                                                const float* __restrict__ invc,
                                                const float* __restrict__ bl1,
                                                float* __restrict__ H2, int N) {
    int wv = threadIdx.x >> 6, lane = threadIdx.x & 63;
    int n = blockIdx.x * 4 + wv;
    if (n >= N) return;
    if (lane >= 40) return;
    int e0 = offs[n], e1 = offs[n + 1];
    float acc = 0.f;
    for (int e = e0; e < e1; ++e) {
        int s = ssrc[e];
        acc += Z[(size_t)s * 80 + lane];
    }
    float v = acc * invc[n] + bl1[lane] + Z[(size_t)n * 80 + 40 + lane];
    H2[(size_t)n * 40 + lane] = v;
}

// ---------------- W_lin pre-convert: Wb[col][k'] bf16, k' = i*48+j, K'=2304 ----------------

__global__ __launch_bounds__(256) void k_wprep(const float* __restrict__ W,
                                               unsigned short* __restrict__ Wb) {
    int idx = blockIdx.x * 256 + threadIdx.x;   // < 48*2304
    if (idx >= 48 * 2304) return;
    int col = idx / 2304;
    int kp = idx - col * 2304;
    int i = kp / 48;
    int j = kp - i * 48;
    float v = 0.f;
    if (col < 40 && i < 40 && j < 40) v = W[((size_t)(i * 40 + j)) * 40 + col];
    Wb[idx] = f2bf_rne(v);
}

// ---------------- k_final_mfma ----------------
// u = atanh(min(||g||^2,0.996))/||g||^2 * ((g x g) @ W) + b, then expmap0/proj/log_softmax.
// (g x g)@W via bf16 MFMA over K'=48*48=2304; A generated on the fly into LDS
// (double-buffered); B fragments loaded directly from global Wb (L2-hot).

__global__ __launch_bounds__(256) void k_final_mfma(const float* __restrict__ H2,
                                                    const unsigned short* __restrict__ Wb,
                                                    const float* __restrict__ blin,
                                                    float* __restrict__ out, int N) {
    constexpr int AS = 104;  // A_lds row stride (bf16 elems); 208 B, 16B-aligned rows
    __shared__ float q_lds[64 * 52];
    __shared__ float alpha_lds[64];
    __shared__ float s2p[256];
    __shared__ __align__(16) unsigned short A_lds[2][64 * AS];

    int tid = threadIdx.x;
    int m0 = blockIdx.x * 64;

    // ---- phase 1: load g (raw), partial s2 ----
    {
        int n = tid >> 2, p = tid & 3;
        int gn = m0 + n;
        float part = 0.f;
        #pragma unroll
        for (int u = 0; u < 10; ++u) {
            int j = p * 10 + u;
            float g = (gn < N) ? H2[(size_t)gn * 40 + j] : 0.f;
            q_lds[n * 52 + j] = g;
            part += g * g;
        }
        if (p == 3) {
            #pragma unroll
            for (int j = 40; j < 48; ++j) q_lds[n * 52 + j] = 0.f;
        }
        s2p[tid] = part;
    }
    __syncthreads();
    if (tid < 64) {
        float s2 = s2p[tid * 4] + s2p[tid * 4 + 1] + s2p[tid * 4 + 2] + s2p[tid * 4 + 3];
        float a = atanhf(fminf(fmaxf(s2, 1e-15f), 0.996f));
        alpha_lds[tid] = a / fmaxf(s2, 1e-30f);   // alpha' = atanh(.)/||g||^2
    }
    __syncthreads();

    int lane = tid & 63;
    int w = __builtin_amdgcn_readfirstlane(tid >> 6);  // 0..3
    int jbase = (w & 1) * 24;
    int ioff = (w >> 1);  // i = 2*ii + ioff for this wave's quarter
    int ml = lane & 15;
    int quad = lane >> 4;

    float qreg[24];
    #pragma unroll
    for (int u = 0; u < 24; ++u) qreg[u] = q_lds[lane * 52 + jbase + u];

    // A-tile generator: A[n][kk] = g_i * g_j for k' = ii*96 + kk
    auto gen = [&](int ii, int b) {
        float qi = q_lds[lane * 52 + 2 * ii + ioff];
        unsigned pk[12];
        #pragma unroll
        for (int v = 0; v < 12; ++v)
            pk[v] = pack_bf16_hu(qi * qreg[2 * v], qi * qreg[2 * v + 1]);
        uint4* dstp = (uint4*)&A_lds[b][lane * AS + w * 24];
        dstp[0] = make_uint4(pk[0], pk[1], pk[2], pk[3]);
        dstp[1] = make_uint4(pk[4], pk[5], pk[6], pk[7]);
        dstp[2] = make_uint4(pk[8], pk[9], pk[10], pk[11]);
    };

    gen(0, 0);
    __syncthreads();

    f32x4 acc[3];
    #pragma unroll
    for (int c = 0; c < 3; ++c) acc[c] = (f32x4){0.f, 0.f, 0.f, 0.f};

    const unsigned short* bw = Wb + (size_t)ml * 2304 + quad * 8;

    for (int ii = 0; ii < 24; ++ii) {
        int buf = ii & 1;
        // B fragments straight from global (L2-resident Wb)
        bf16x8 bfr[3][3];
        #pragma unroll
        for (int s = 0; s < 3; ++s)
            #pragma unroll
            for (int c = 0; c < 3; ++c)
                bfr[s][c] = *(const bf16x8*)&bw[(size_t)c * 16 * 2304 + ii * 96 + s * 32];
        // generate next A tile while B loads are in flight
        if (ii < 23) gen(ii + 1, buf ^ 1);
        // A fragments from LDS
        const unsigned short* arow = &A_lds[buf][(w * 16 + ml) * AS + quad * 8];
        bf16x8 af[3];
        #pragma unroll
        for (int s = 0; s < 3; ++s) af[s] = *(const bf16x8*)&arow[s * 32];
        #pragma unroll
        for (int s = 0; s < 3; ++s)
            #pragma unroll
            for (int c = 0; c < 3; ++c)
                acc[c] = __builtin_amdgcn_mfma_f32_16x16x32_bf16(af[s], bfr[s][c], acc[c], 0, 0, 0);
        __syncthreads();
    }

    // ---- epilogue: C/D layout col = lane&15 (+16c), row = quad*4 + r ----
    float bcol[3];
    #pragma unroll
    for (int c = 0; c < 3; ++c) {
        int col = c * 16 + ml;
        bcol[c] = (col < 40) ? blin[col] : 0.f;
    }
    bool v2 = (ml < 8);  // col-tile 2 valid only for cols 32..39

    #pragma unroll
    for (int r = 0; r < 4; ++r) {
        int nloc = w * 16 + quad * 4 + r;
        float al = alpha_lds[nloc];
        float u0 = al * acc[0][r] + bcol[0];
        float u1 = al * acc[1][r] + bcol[1];
        float u2 = v2 ? (al * acc[2][r] + bcol[2]) : 0.f;
        float un2 = u0 * u0 + u1 * u1 + u2 * u2;
        #pragma unroll
        for (int m = 1; m < 16; m <<= 1) un2 += __shfl_xor(un2, m);
        float un = fmaxf(sqrtf(un2), 1e-15f);
        float tnh = tanhf(un);
        float gma = tnh / un;                       // expmap0 scale
        float ps = (tnh > 0.996f) ? (0.996f / tnh) : 1.0f;  // proj scale
        float s = gma * ps;
        float l0 = s * u0, l1 = s * u1, l2 = s * u2;
        float mx = fmaxf(l0, l1);
        if (v2) mx = fmaxf(mx, l2);
        #pragma unroll
        for (int m = 1; m < 16; m <<= 1) mx = fmaxf(mx, __shfl_xor(mx, m));
        float se = expf(l0 - mx) + expf(l1 - mx) + (v2 ? expf(l2 - mx) : 0.f);
        #pragma unroll
        for (int m = 1; m < 16; m <<= 1) se += __shfl_xor(se, m);
        float lse = logf(se);
        int gn = m0 + nloc;
        if (gn < N) {
            out[(size_t)gn * 40 + ml] = l0 - mx - lse;
            out[(size_t)gn * 40 + 16 + ml] = l1 - mx - lse;
            if (v2) out[(size_t)gn * 40 + 32 + ml] = l2 - mx - lse;
        }
    }
}

// ---------------- launch ----------------

extern "C" void kernel_launch(void* const* d_in, const int* in_sizes, int n_in,
                              void* d_out, int out_size, void* d_ws, size_t ws_size,
                              hipStream_t stream) {
    const float* x    = (const float*)d_in[0];
    const int*   ei   = (const int*)d_in[1];
    const float* Wl0  = (const float*)d_in[2];
    const float* bl0  = (const float*)d_in[3];
    const float* Wr0  = (const float*)d_in[4];
    const float* Wl1  = (const float*)d_in[5];
    const float* bl1  = (const float*)d_in[6];
    const float* Wr1  = (const float*)d_in[7];
    const float* Wlin = (const float*)d_in[8];
    const float* blin = (const float*)d_in[9];
    int N = in_sizes[0] / 256;
    int E = in_sizes[1] / 2;
    const int* src = ei;
    const int* dst = ei + E;

    char* ws = (char*)d_ws;
    size_t off = 0;
    auto carve = [&](size_t bytes) -> char* {
        char* p = ws + off;
        off = (off + bytes + 255) & ~(size_t)255;
        return p;
    };
    int*   deg    = (int*)carve((size_t)N * 4);
    int*   cursor = (int*)carve((size_t)N * 4);
    int*   offs   = (int*)carve((size_t)(N + 1) * 4);
    float* invc   = (float*)carve((size_t)N * 4);
    int*   ssrc   = (int*)carve((size_t)E * 4);
    float* Y      = (float*)carve((size_t)N * 512 * 4);
    float* Hb     = (float*)carve((size_t)N * 256 * 4);
    float* Z      = (float*)carve((size_t)N * 80 * 4);
    float* H2     = (float*)carve((size_t)N * 40 * 4);
    // Wb (48*2304 bf16 = 216 KB) aliases Y, which is dead after combine0
    unsigned short* Wb = (unsigned short*)Y;

    hipMemsetAsync(deg, 0, (size_t)N * 4, stream);
    hipMemsetAsync(cursor, 0, (size_t)N * 4, stream);

    k_count<<<(E + 255) / 256, 256, 0, stream>>>(dst, deg, E);
    k_scan<<<1, 1024, 0, stream>>>(deg, offs, invc, N);
    k_scatter<<<(E + 255) / 256, 256, 0, stream>>>(src, dst, offs, cursor, ssrc, E);
    gemm0<<<dim3((N + 63) / 64, 8), 256, 0, stream>>>(x, Wl0, Wr0, Y, N);
    combine0<<<(N + 3) / 4, 256, 0, stream>>>(Y, offs, ssrc, invc, bl0, Hb, N);
    k_wprep<<<(48 * 2304) / 256, 256, 0, stream>>>(Wlin, Wb);   // after combine0 (Y alias)
    gemm1<<<(N + 63) / 64, 256, 0, stream>>>(Hb, Wl1, Wr1, Z, N);
    combine1<<<(N + 3) / 4, 256, 0, stream>>>(Z, offs, ssrc, invc, bl1, H2, N);
    k_final_mfma<<<(N + 63) / 64, 256, 0, stream>>>(H2, Wb, blin, (float*)d_out, N);
}

// Round 3
// 682.870 us; speedup vs baseline: 1.2599x; 1.1862x over previous
//
#include <hip/hip_runtime.h>
#include <math.h>

// N=50000, F=256, H=256, C=40, E=800000; CURV=1, EPS=4e-3 -> maxnorm=0.996

typedef short bf16x8 __attribute__((ext_vector_type(8)));
typedef float f32x4 __attribute__((ext_vector_type(4)));

// pack two fp32 -> bf16x2 (round-half-up) : low short = a, high short = b
__device__ inline unsigned pack_bf16_hu(float a, float b) {
    unsigned ua = __float_as_uint(a) + 0x8000u;
    unsigned ub = __float_as_uint(b) + 0x8000u;
    return __builtin_amdgcn_perm(ub, ua, 0x07060302u);
}

__device__ inline unsigned short f2bf_rne(float x) {
    unsigned u = __float_as_uint(x);
    unsigned r = (u + 0x7fffu + ((u >> 16) & 1u)) >> 16;
    return (unsigned short)r;
}

// split (a,b) into hi bf16 pair + residual-lo bf16 pair (packed uints)
__device__ inline void split2(float a, float b, unsigned* hw, unsigned* lw) {
    unsigned ua = __float_as_uint(a) + 0x8000u;
    unsigned ub = __float_as_uint(b) + 0x8000u;
    *hw = __builtin_amdgcn_perm(ub, ua, 0x07060302u);
    float ra = a - __uint_as_float(ua & 0xFFFF0000u);
    float rb = b - __uint_as_float(ub & 0xFFFF0000u);
    unsigned va = __float_as_uint(ra) + 0x8000u;
    unsigned vb = __float_as_uint(rb) + 0x8000u;
    *lw = __builtin_amdgcn_perm(vb, va, 0x07060302u);
}

__device__ inline void split8(const float f[8], bf16x8* hi, bf16x8* lo) {
    union { unsigned u[4]; bf16x8 v; } H, L;
    #pragma unroll
    for (int i = 0; i < 4; ++i) split2(f[2 * i], f[2 * i + 1], &H.u[i], &L.u[i]);
    *hi = H.v; *lo = L.v;
}

__device__ inline bf16x8 bfzero() {
    union { unsigned u[4]; bf16x8 v; } Z;
    Z.u[0] = Z.u[1] = Z.u[2] = Z.u[3] = 0;
    return Z.v;
}

// ---------------- CSR build ----------------

__global__ void k_count(const int* __restrict__ dst, int* __restrict__ deg, int E) {
    int e = blockIdx.x * 256 + threadIdx.x;
    if (e < E) atomicAdd(&deg[dst[e]], 1);
}

__global__ __launch_bounds__(1024) void k_scan(const int* __restrict__ deg,
                                               int* __restrict__ offs,
                                               float* __restrict__ invc, int N) {
    __shared__ int wtot[16];
    int tid = threadIdx.x, lane = tid & 63, wid = tid >> 6;
    int running = 0;
    for (int base = 0; base < N; base += 1024) {
        int i = base + tid;
        int v = (i < N) ? deg[i] : 0;
        if (i < N) invc[i] = 1.0f / (float)max(v, 1);
        int s = v;
        #pragma unroll
        for (int d = 1; d < 64; d <<= 1) {
            int t = __shfl_up(s, d);
            if (lane >= d) s += t;
        }
        if (lane == 63) wtot[wid] = s;
        __syncthreads();
        int wpre = 0, tot = 0;
        #pragma unroll
        for (int t = 0; t < 16; ++t) {
            int x = wtot[t];
            tot += x;
            if (t < wid) wpre += x;
        }
        if (i < N) offs[i] = running + wpre + s - v;   // exclusive
        running += tot;
        __syncthreads();
    }
    if (tid == 0) offs[N] = running;
}

__global__ void k_scatter(const int* __restrict__ src, const int* __restrict__ dst,
                          const int* __restrict__ offs, int* __restrict__ cursor,
                          int* __restrict__ ssrc, int E) {
    int e = blockIdx.x * 256 + threadIdx.x;
    if (e >= E) return;
    int d = dst[e];
    int pos = offs[d] + atomicAdd(&cursor[d], 1);
    ssrc[pos] = src[e];
}

// ---------------- weight prep: transposed split-bf16 ----------------
// Wt0[n][k], n<256 -> Wl0[k][n], else Wr0[k][n-256]   (512 x 256)

__global__ __launch_bounds__(256) void k_wsplit0(const float* __restrict__ Wl,
                                                 const float* __restrict__ Wr,
                                                 unsigned short* __restrict__ Wth,
                                                 unsigned short* __restrict__ Wtl) {
    int idx = blockIdx.x * 256 + threadIdx.x;   // < 512*256
    int n = idx >> 8, k = idx & 255;
    float v = (n < 256) ? Wl[k * 256 + n] : Wr[k * 256 + (n - 256)];
    unsigned short h = f2bf_rne(v);
    float hf = __uint_as_float(((unsigned)h) << 16);
    Wth[idx] = h;
    Wtl[idx] = f2bf_rne(v - hf);
}

// Wt1[n][k], n<40 -> Wl1[k][n], else Wr1[k][n-40]   (80 x 256)

__global__ __launch_bounds__(256) void k_wsplit1(const float* __restrict__ Wl,
                                                 const float* __restrict__ Wr,
                                                 unsigned short* __restrict__ Wth,
                                                 unsigned short* __restrict__ Wtl) {
    int idx = blockIdx.x * 256 + threadIdx.x;   // < 80*256
    if (idx >= 80 * 256) return;
    int n = idx >> 8, k = idx & 255;
    float v = (n < 40) ? Wl[k * 40 + n] : Wr[k * 40 + (n - 40)];
    unsigned short h = f2bf_rne(v);
    float hf = __uint_as_float(((unsigned)h) << 16);
    Wth[idx] = h;
    Wtl[idx] = f2bf_rne(v - hf);
}

// ---------------- gemm0: Y[N,512] = X[N,256] @ Wt0^T via bf16x3 MFMA ----------------
// block: 256 thr = 4 waves; tile M=64 (shared), each wave owns 64 cols.
// grid (ceil(N/64), 2). A-frags: X fp32 loaded+split in regs; B-frags from L2 Wt.

__global__ __launch_bounds__(256) void gemm0_mfma(const float* __restrict__ X,
                                                  const unsigned short* __restrict__ Bh,
                                                  const unsigned short* __restrict__ Bl,
                                                  float* __restrict__ Y, int N) {
    int tid = threadIdx.x;
    int lane = tid & 63;
    int w = __builtin_amdgcn_readfirstlane(tid >> 6);
    int ml = lane & 15, quad = lane >> 4;
    int m0 = blockIdx.x * 64;
    int nbase = blockIdx.y * 256 + w * 64;

    f32x4 acc[4][4];
    #pragma unroll
    for (int a = 0; a < 4; ++a)
        #pragma unroll
        for (int b = 0; b < 4; ++b) acc[a][b] = (f32x4){0.f, 0.f, 0.f, 0.f};

    int arow[4]; bool av[4];
    #pragma unroll
    for (int mf = 0; mf < 4; ++mf) {
        arow[mf] = m0 + mf * 16 + ml;
        av[mf] = arow[mf] < N;
    }

    for (int kc = 0; kc < 256; kc += 32) {
        int ko = kc + quad * 8;
        bf16x8 ah[4], al[4];
        #pragma unroll
        for (int mf = 0; mf < 4; ++mf) {
            float f[8];
            if (av[mf]) {
                float4 x0 = *(const float4*)&X[(size_t)arow[mf] * 256 + ko];
                float4 x1 = *(const float4*)&X[(size_t)arow[mf] * 256 + ko + 4];
                f[0] = x0.x; f[1] = x0.y; f[2] = x0.z; f[3] = x0.w;
                f[4] = x1.x; f[5] = x1.y; f[6] = x1.z; f[7] = x1.w;
            } else {
                #pragma unroll
                for (int t = 0; t < 8; ++t) f[t] = 0.f;
            }
            split8(f, &ah[mf], &al[mf]);
        }
        #pragma unroll
        for (int nf = 0; nf < 4; ++nf) {
            size_t bo = (size_t)(nbase + nf * 16 + ml) * 256 + ko;
            bf16x8 bh = *(const bf16x8*)&Bh[bo];
            bf16x8 bl = *(const bf16x8*)&Bl[bo];
            #pragma unroll
            for (int mf = 0; mf < 4; ++mf) {
                acc[mf][nf] = __builtin_amdgcn_mfma_f32_16x16x32_bf16(ah[mf], bh, acc[mf][nf], 0, 0, 0);
                acc[mf][nf] = __builtin_amdgcn_mfma_f32_16x16x32_bf16(ah[mf], bl, acc[mf][nf], 0, 0, 0);
                acc[mf][nf] = __builtin_amdgcn_mfma_f32_16x16x32_bf16(al[mf], bh, acc[mf][nf], 0, 0, 0);
            }
        }
    }
    #pragma unroll
    for (int mf = 0; mf < 4; ++mf)
        #pragma unroll
        for (int r = 0; r < 4; ++r) {
            int row = m0 + mf * 16 + quad * 4 + r;
            if (row < N) {
                #pragma unroll
                for (int nf = 0; nf < 4; ++nf)
                    Y[(size_t)row * 512 + nbase + nf * 16 + ml] = acc[mf][nf][r];
            }
        }
}

// ---------------- combine0: h = relu(agg(Y_l)/cnt + bl0 + Y_r), write split bf16 ----------------

__global__ __launch_bounds__(256) void combine0(const float* __restrict__ Y,
                                                const int* __restrict__ offs,
                                                const int* __restrict__ ssrc,
                                                const float* __restrict__ invc,
                                                const float* __restrict__ bl0,
                                                unsigned short* __restrict__ Hh,
                                                unsigned short* __restrict__ Hl, int N) {
    int wv = threadIdx.x >> 6, lane = threadIdx.x & 63;
    int n = blockIdx.x * 4 + wv;
    if (n >= N) return;
    int e0 = offs[n], e1 = offs[n + 1];
    float4 acc = make_float4(0.f, 0.f, 0.f, 0.f);
    for (int e = e0; e < e1; ++e) {
        int s = ssrc[e];
        float4 v = *(const float4*)&Y[(size_t)s * 512 + lane * 4];
        acc.x += v.x; acc.y += v.y; acc.z += v.z; acc.w += v.w;
    }
    float ic = invc[n];
    float4 b = *(const float4*)&bl0[lane * 4];
    float4 yr = *(const float4*)&Y[(size_t)n * 512 + 256 + lane * 4];
    float hx = fmaxf(acc.x * ic + b.x + yr.x, 0.f);
    float hy = fmaxf(acc.y * ic + b.y + yr.y, 0.f);
    float hz = fmaxf(acc.z * ic + b.z + yr.z, 0.f);
    float hw = fmaxf(acc.w * ic + b.w + yr.w, 0.f);
    unsigned h0, h1, l0, l1;
    split2(hx, hy, &h0, &l0);
    split2(hz, hw, &h1, &l1);
    *(uint2*)&Hh[(size_t)n * 256 + lane * 4] = make_uint2(h0, h1);
    *(uint2*)&Hl[(size_t)n * 256 + lane * 4] = make_uint2(l0, l1);
}

// ---------------- gemm1: Z[N,80] = H[N,256] @ Wt1^T via bf16x3 MFMA ----------------
// block: 4 waves, each wave 64 rows (block M=256), all 5 col-frags.

__global__ __launch_bounds__(256) void gemm1_mfma(const unsigned short* __restrict__ Ah,
                                                  const unsigned short* __restrict__ Al,
                                                  const unsigned short* __restrict__ Bh,
                                                  const unsigned short* __restrict__ Bl,
                                                  float* __restrict__ Z, int N) {
    int tid = threadIdx.x;
    int lane = tid & 63;
    int w = __builtin_amdgcn_readfirstlane(tid >> 6);
    int ml = lane & 15, quad = lane >> 4;
    int m0 = blockIdx.x * 256 + w * 64;

    f32x4 acc[4][5];
    #pragma unroll
    for (int a = 0; a < 4; ++a)
        #pragma unroll
        for (int b = 0; b < 5; ++b) acc[a][b] = (f32x4){0.f, 0.f, 0.f, 0.f};

    int arow[4]; bool av[4];
    #pragma unroll
    for (int mf = 0; mf < 4; ++mf) {
        arow[mf] = m0 + mf * 16 + ml;
        av[mf] = arow[mf] < N;
    }

    for (int kc = 0; kc < 256; kc += 32) {
        int ko = kc + quad * 8;
        bf16x8 ah[4], al[4];
        #pragma unroll
        for (int mf = 0; mf < 4; ++mf) {
            size_t ao = (size_t)arow[mf] * 256 + ko;
            ah[mf] = av[mf] ? *(const bf16x8*)&Ah[ao] : bfzero();
            al[mf] = av[mf] ? *(const bf16x8*)&Al[ao] : bfzero();
        }
        #pragma unroll
        for (int nf = 0; nf < 5; ++nf) {
            size_t bo = (size_t)(nf * 16 + ml) * 256 + ko;
            bf16x8 bh = *(const bf16x8*)&Bh[bo];
            bf16x8 bl = *(const bf16x8*)&Bl[bo];
            #pragma unroll
            for (int mf = 0; mf < 4; ++mf) {
                acc[mf][nf] = __builtin_amdgcn_mfma_f32_16x16x32_bf16(ah[mf], bh, acc[mf][nf], 0, 0, 0);
                acc[mf][nf] = __builtin_amdgcn_mfma_f32_16x16x32_bf16(ah[mf], bl, acc[mf][nf], 0, 0, 0);
                acc[mf][nf] = __builtin_amdgcn_mfma_f32_16x16x32_bf16(al[mf], bh, acc[mf][nf], 0, 0, 0);
            }
        }
    }
    #pragma unroll
    for (int mf = 0; mf < 4; ++mf)
        #pragma unroll
        for (int r = 0; r < 4; ++r) {
            int row = m0 + mf * 16 + quad * 4 + r;
            if (row < N) {
                #pragma unroll
                for (int nf = 0; nf < 5; ++nf)
                    Z[(size_t)row * 80 + nf * 16 + ml] = acc[mf][nf][r];
            }
        }
}

// ---------------- combine1 ----------------

__global__ __launch_bounds__(256) void combine1(const float* __restrict__ Z,
                                                const int* __restrict__ offs,
                                                const int* __restrict__ ssrc,
                                                const float* __restrict__ invc,
                                                const float* __restrict__ bl1,
                                                float* __restrict__ H2, int N) {
    int wv = threadIdx.x >> 6, lane = threadIdx.x & 63;
    int n = blockIdx.x * 4 + wv;
    if (n >= N) return;
    if (lane >= 40) return;
    int e0 = offs[n], e1 = offs[n + 1];
    float acc = 0.f;
    for (int e = e0; e < e1; ++e) {
        int s = ssrc[e];
        acc += Z[(size_t)s * 80 + lane];
    }
    float v = acc * invc[n] + bl1[lane] + Z[(size_t)n * 80 + 40 + lane];
    H2[(size_t)n * 40 + lane] = v;
}

// ---------------- W_lin pre-convert: Wb[col][k'] bf16, k' = i*48+j, K'=2304 ----------------

__global__ __launch_bounds__(256) void k_wprep(const float* __restrict__ W,
                                               unsigned short* __restrict__ Wb) {
    int idx = blockIdx.x * 256 + threadIdx.x;   // < 48*2304
    if (idx >= 48 * 2304) return;
    int col = idx / 2304;
    int kp = idx - col * 2304;
    int i = kp / 48;
    int j = kp - i * 48;
    float v = 0.f;
    if (col < 40 && i < 40 && j < 40) v = W[((size_t)(i * 40 + j)) * 40 + col];
    Wb[idx] = f2bf_rne(v);
}

// ---------------- k_final_mfma ----------------

__global__ __launch_bounds__(256) void k_final_mfma(const float* __restrict__ H2,
                                                    const unsigned short* __restrict__ Wb,
                                                    const float* __restrict__ blin,
                                                    float* __restrict__ out, int N) {
    constexpr int AS = 104;
    __shared__ float q_lds[64 * 52];
    __shared__ float alpha_lds[64];
    __shared__ float s2p[256];
    __shared__ __align__(16) unsigned short A_lds[2][64 * AS];

    int tid = threadIdx.x;
    int m0 = blockIdx.x * 64;

    {
        int n = tid >> 2, p = tid & 3;
        int gn = m0 + n;
        float part = 0.f;
        #pragma unroll
        for (int u = 0; u < 10; ++u) {
            int j = p * 10 + u;
            float g = (gn < N) ? H2[(size_t)gn * 40 + j] : 0.f;
            q_lds[n * 52 + j] = g;
            part += g * g;
        }
        if (p == 3) {
            #pragma unroll
            for (int j = 40; j < 48; ++j) q_lds[n * 52 + j] = 0.f;
        }
        s2p[tid] = part;
    }
    __syncthreads();
    if (tid < 64) {
        float s2 = s2p[tid * 4] + s2p[tid * 4 + 1] + s2p[tid * 4 + 2] + s2p[tid * 4 + 3];
        float a = atanhf(fminf(fmaxf(s2, 1e-15f), 0.996f));
        alpha_lds[tid] = a / fmaxf(s2, 1e-30f);
    }
    __syncthreads();

    int lane = tid & 63;
    int w = __builtin_amdgcn_readfirstlane(tid >> 6);
    int jbase = (w & 1) * 24;
    int ioff = (w >> 1);
    int ml = lane & 15;
    int quad = lane >> 4;

    float qreg[24];
    #pragma unroll
    for (int u = 0; u < 24; ++u) qreg[u] = q_lds[lane * 52 + jbase + u];

    auto gen = [&](int ii, int b) {
        float qi = q_lds[lane * 52 + 2 * ii + ioff];
        unsigned pk[12];
        #pragma unroll
        for (int v = 0; v < 12; ++v)
            pk[v] = pack_bf16_hu(qi * qreg[2 * v], qi * qreg[2 * v + 1]);
        uint4* dstp = (uint4*)&A_lds[b][lane * AS + w * 24];
        dstp[0] = make_uint4(pk[0], pk[1], pk[2], pk[3]);
        dstp[1] = make_uint4(pk[4], pk[5], pk[6], pk[7]);
        dstp[2] = make_uint4(pk[8], pk[9], pk[10], pk[11]);
    };

    gen(0, 0);
    __syncthreads();

    f32x4 acc[3];
    #pragma unroll
    for (int c = 0; c < 3; ++c) acc[c] = (f32x4){0.f, 0.f, 0.f, 0.f};

    const unsigned short* bw = Wb + (size_t)ml * 2304 + quad * 8;

    for (int ii = 0; ii < 24; ++ii) {
        int buf = ii & 1;
        bf16x8 bfr[3][3];
        #pragma unroll
        for (int s = 0; s < 3; ++s)
            #pragma unroll
            for (int c = 0; c < 3; ++c)
                bfr[s][c] = *(const bf16x8*)&bw[(size_t)c * 16 * 2304 + ii * 96 + s * 32];
        if (ii < 23) gen(ii + 1, buf ^ 1);
        const unsigned short* arow = &A_lds[buf][(w * 16 + ml) * AS + quad * 8];
        bf16x8 af[3];
        #pragma unroll
        for (int s = 0; s < 3; ++s) af[s] = *(const bf16x8*)&arow[s * 32];
        #pragma unroll
        for (int s = 0; s < 3; ++s)
            #pragma unroll
            for (int c = 0; c < 3; ++c)
                acc[c] = __builtin_amdgcn_mfma_f32_16x16x32_bf16(af[s], bfr[s][c], acc[c], 0, 0, 0);
        __syncthreads();
    }

    float bcol[3];
    #pragma unroll
    for (int c = 0; c < 3; ++c) {
        int col = c * 16 + ml;
        bcol[c] = (col < 40) ? blin[col] : 0.f;
    }
    bool v2 = (ml < 8);

    #pragma unroll
    for (int r = 0; r < 4; ++r) {
        int nloc = w * 16 + quad * 4 + r;
        float al = alpha_lds[nloc];
        float u0 = al * acc[0][r] + bcol[0];
        float u1 = al * acc[1][r] + bcol[1];
        float u2 = v2 ? (al * acc[2][r] + bcol[2]) : 0.f;
        float un2 = u0 * u0 + u1 * u1 + u2 * u2;
        #pragma unroll
        for (int m = 1; m < 16; m <<= 1) un2 += __shfl_xor(un2, m);
        float un = fmaxf(sqrtf(un2), 1e-15f);
        float tnh = tanhf(un);
        float gma = tnh / un;
        float ps = (tnh > 0.996f) ? (0.996f / tnh) : 1.0f;
        float s = gma * ps;
        float l0 = s * u0, l1 = s * u1, l2 = s * u2;
        float mx = fmaxf(l0, l1);
        if (v2) mx = fmaxf(mx, l2);
        #pragma unroll
        for (int m = 1; m < 16; m <<= 1) mx = fmaxf(mx, __shfl_xor(mx, m));
        float se = expf(l0 - mx) + expf(l1 - mx) + (v2 ? expf(l2 - mx) : 0.f);
        #pragma unroll
        for (int m = 1; m < 16; m <<= 1) se += __shfl_xor(se, m);
        float lse = logf(se);
        int gn = m0 + nloc;
        if (gn < N) {
            out[(size_t)gn * 40 + ml] = l0 - mx - lse;
            out[(size_t)gn * 40 + 16 + ml] = l1 - mx - lse;
            if (v2) out[(size_t)gn * 40 + 32 + ml] = l2 - mx - lse;
        }
    }
}

// ---------------- launch ----------------

extern "C" void kernel_launch(void* const* d_in, const int* in_sizes, int n_in,
                              void* d_out, int out_size, void* d_ws, size_t ws_size,
                              hipStream_t stream) {
    const float* x    = (const float*)d_in[0];
    const int*   ei   = (const int*)d_in[1];
    const float* Wl0  = (const float*)d_in[2];
    const float* bl0  = (const float*)d_in[3];
    const float* Wr0  = (const float*)d_in[4];
    const float* Wl1  = (const float*)d_in[5];
    const float* bl1  = (const float*)d_in[6];
    const float* Wr1  = (const float*)d_in[7];
    const float* Wlin = (const float*)d_in[8];
    const float* blin = (const float*)d_in[9];
    int N = in_sizes[0] / 256;
    int E = in_sizes[1] / 2;
    const int* src = ei;
    const int* dst = ei + E;

    char* ws = (char*)d_ws;
    size_t off = 0;
    auto carve = [&](size_t bytes) -> char* {
        char* p = ws + off;
        off = (off + bytes + 255) & ~(size_t)255;
        return p;
    };
    int*   deg    = (int*)carve((size_t)N * 4);
    int*   cursor = (int*)carve((size_t)N * 4);
    int*   offs   = (int*)carve((size_t)(N + 1) * 4);
    float* invc   = (float*)carve((size_t)N * 4);
    int*   ssrc   = (int*)carve((size_t)E * 4);
    float* Y      = (float*)carve((size_t)N * 512 * 4);
    unsigned short* Hh = (unsigned short*)carve((size_t)N * 256 * 2);
    unsigned short* Hl = (unsigned short*)carve((size_t)N * 256 * 2);
    float* Z      = (float*)carve((size_t)N * 80 * 4);
    float* H2     = (float*)carve((size_t)N * 40 * 4);
    // Wb (48*2304 bf16 = 221 KB) aliases Y (dead after combine0)
    unsigned short* Wb = (unsigned short*)Y;
    // split weights (606 KB total) alias H2 (written only at combine1, after gemm1)
    unsigned short* Wth  = (unsigned short*)H2;
    unsigned short* Wtl  = Wth + 512 * 256;
    unsigned short* Wt1h = Wtl + 512 * 256;
    unsigned short* Wt1l = Wt1h + 80 * 256;

    hipMemsetAsync(deg, 0, (size_t)N * 4, stream);
    hipMemsetAsync(cursor, 0, (size_t)N * 4, stream);

    k_count<<<(E + 255) / 256, 256, 0, stream>>>(dst, deg, E);
    k_scan<<<1, 1024, 0, stream>>>(deg, offs, invc, N);
    k_scatter<<<(E + 255) / 256, 256, 0, stream>>>(src, dst, offs, cursor, ssrc, E);
    k_wsplit0<<<(512 * 256) / 256, 256, 0, stream>>>(Wl0, Wr0, Wth, Wtl);
    k_wsplit1<<<(80 * 256 + 255) / 256, 256, 0, stream>>>(Wl1, Wr1, Wt1h, Wt1l);
    gemm0_mfma<<<dim3((N + 63) / 64, 2), 256, 0, stream>>>(x, Wth, Wtl, Y, N);
    combine0<<<(N + 3) / 4, 256, 0, stream>>>(Y, offs, ssrc, invc, bl0, Hh, Hl, N);
    k_wprep<<<(48 * 2304) / 256, 256, 0, stream>>>(Wlin, Wb);   // after combine0 (Y alias)
    gemm1_mfma<<<(N + 255) / 256, 256, 0, stream>>>(Hh, Hl, Wt1h, Wt1l, Z, N);
    combine1<<<(N + 3) / 4, 256, 0, stream>>>(Z, offs, ssrc, invc, bl1, H2, N);
    k_final_mfma<<<(N + 63) / 64, 256, 0, stream>>>(H2, Wb, blin, (float*)d_out, N);
}